// Round 10
// baseline (11.958 us; speedup 1.0000x reference)
//
#include <hip/hip_runtime.h>

#define EPSF 1e-4f
#define H    256
#define W    256
#define HO   248           // valid output dim: 256 - 9 + 1
#define OW   24            // output columns per block
#define OH   16            // output rows per block
#define CSTR 33            // padded LDS row stride
#define GX   11            // ceil(248/24)
#define GY   16            // ceil(248/16)
#define NBLK (GX*GY)       // 176 blocks per batch

// Separable NCC, single kernel, deterministic last-block finish.
// Write side (round-8 protocol, never falsified): relaxed agent store of the
//   block partial to its OWN slot -> s_waitcnt vmcnt(0) (store ack'd at the
//   coherence point) -> relaxed fetch_add on a per-batch counter in its OWN
//   256B line. Counter-order implies partial-completion.
// Read side (round-5 mechanism, proven correct): the 176th arriver (mod-NBLK
//   test: works for any 0xAA-poisoned start, wrap-safe) issues an agent
//   acquire fence + ACQUIRE loads — sc-bit bypass, cannot be served from a
//   stale XCD L2 line (round 8's failure mode). Fixed tid-ordered sum tree
//   -> bitwise-deterministic output regardless of which block wins.
__global__ __launch_bounds__(128) void ncc_kernel(
    const float* __restrict__ x1, const float* __restrict__ x2,
    float* __restrict__ ws, float* __restrict__ out)
{
    __shared__ float C[5][OH][CSTR];   // 10560 B
    __shared__ float warp_part[2];
    __shared__ int   winner_flag;

    const int b  = blockIdx.z;
    const int j0 = blockIdx.x * OW;
    const int i0 = blockIdx.y * OH;
    const int tid = threadIdx.x;

    const float* p1 = x1 + (size_t)b * (H * W);
    const float* p2 = x2 + (size_t)b * (H * W);

    // ---------------- Phase 1: vertical column sums ----------------
    // thread -> (pixel column c = tid&31, row-group g = tid>>5); each of the
    // 4 groups produces 4 output rows via a register slide (12 input rows).
    {
        const int c = tid & 31;        // 0..31
        const int g = tid >> 5;        // 0..3
        const int j = j0 + c;
        const bool jok = (j < W);
        const int ibase = i0 + g * 4;

        float av[12], bv[12];
        #pragma unroll
        for (int r = 0; r < 12; ++r) {
            const int i = ibase + r;
            const bool ok = jok && (i < H);
            av[r] = ok ? p1[i * W + j] : 0.0f;
            bv[r] = ok ? p2[i * W + j] : 0.0f;
        }

        float s1 = 0.0f, s2 = 0.0f, s11 = 0.0f, s22 = 0.0f, s12 = 0.0f;
        #pragma unroll
        for (int r = 0; r < 9; ++r) {
            s1 += av[r];
            s2 += bv[r];
            s11 = fmaf(av[r], av[r], s11);
            s22 = fmaf(bv[r], bv[r], s22);
            s12 = fmaf(av[r], bv[r], s12);
        }
        const int t0 = g * 4;
        C[0][t0][c] = s1;  C[1][t0][c] = s2;
        C[2][t0][c] = s11; C[3][t0][c] = s22; C[4][t0][c] = s12;

        #pragma unroll
        for (int tt = 1; tt < 4; ++tt) {
            const float an = av[tt + 8], bn = bv[tt + 8];
            const float ao = av[tt - 1], bo = bv[tt - 1];
            s1 += an - ao;
            s2 += bn - bo;
            s11 = fmaf(an, an, s11); s11 = fmaf(-ao, ao, s11);
            s22 = fmaf(bn, bn, s22); s22 = fmaf(-bo, bo, s22);
            s12 = fmaf(an, bn, s12); s12 = fmaf(-ao, bo, s12);
            const int t = t0 + tt;
            C[0][t][c] = s1;  C[1][t][c] = s2;
            C[2][t][c] = s11; C[3][t][c] = s22; C[4][t][c] = s12;
        }
    }
    __syncthreads();

    // ---------------- Phase 2: horizontal sliding window ----------------
    // thread -> (output row t = tid&15, column group jg = tid>>4 of 3 outputs)
    // bank = (t + 3*jg + k) mod 32 -> ~2-way aliasing (free).
    float contrib = 0.0f;
    {
        const int t   = tid & 15;      // 0..15
        const int jg  = tid >> 4;      // 0..7
        const int jc0 = jg * 3;
        const int t_out = i0 + t;

        float cv[11];
        float Wq[3][5];
        #pragma unroll
        for (int q = 0; q < 5; ++q) {
            #pragma unroll
            for (int k = 0; k < 11; ++k)
                cv[k] = C[q][t][jc0 + k];
            float w = cv[0];
            #pragma unroll
            for (int k = 1; k < 9; ++k) w += cv[k];
            Wq[0][q] = w;
            Wq[1][q] = Wq[0][q] - cv[0] + cv[9];
            Wq[2][q] = Wq[1][q] - cv[1] + cv[10];
        }

        const float inv_n = 1.0f / 81.0f;
        #pragma unroll
        for (int m = 0; m < 3; ++m) {
            const int j_out = j0 + jc0 + m;
            if (t_out < HO && j_out < HO) {
                const float s1  = Wq[m][0], s2  = Wq[m][1];
                const float s11 = Wq[m][2], s22 = Wq[m][3], s12 = Wq[m][4];
                const float mu1 = s1 * inv_n;
                const float mu2 = s2 * inv_n;
                const float v1  = fmaf(-mu1, mu1, s11 * inv_n) + EPSF;
                const float v2  = fmaf(-mu2, mu2, s22 * inv_n) + EPSF;
                const float cross = fmaf(-mu1, s2, s12);
                contrib += cross * rsqrtf(v1 * v2);
            }
        }
    }

    // ---------------- block reduce -> one partial per block ----------------
    #pragma unroll
    for (int off = 32; off >= 1; off >>= 1)
        contrib += __shfl_down(contrib, off, 64);

    const int lane = tid & 63;
    const int wid  = tid >> 6;
    if (lane == 0) warp_part[wid] = contrib;
    __syncthreads();

    // ---------------- deterministic last-block finish ----------------
    if (tid == 0) {
        const int blk = blockIdx.y * GX + blockIdx.x;
        const float part = warp_part[0] + warp_part[1];
        // partial -> own slot (coherence-point store, no fence)
        __hip_atomic_store(&ws[b * NBLK + blk], part,
                           __ATOMIC_RELAXED, __HIP_MEMORY_SCOPE_AGENT);
        // store must be ack'd before our count becomes visible
        asm volatile("s_waitcnt vmcnt(0)" ::: "memory");
        // per-batch counter in its own 256B line: u32 index 4096 + b*64
        unsigned* cnt = (unsigned*)ws + 4096 + b * 64;
        const unsigned old = __hip_atomic_fetch_add(cnt, 1u,
                           __ATOMIC_RELAXED, __HIP_MEMORY_SCOPE_AGENT);
        winner_flag = ((old % (unsigned)NBLK) == (unsigned)(NBLK - 1)) ? 1 : 0;
    }
    __syncthreads();

    if (winner_flag && tid < 64) {
        // acquire: invalidate any stale local-L2 copies before reading
        __builtin_amdgcn_fence(__ATOMIC_ACQUIRE, "agent");
        const float* base = ws + (size_t)b * NBLK;
        float v = __hip_atomic_load(&base[tid], __ATOMIC_ACQUIRE,
                                    __HIP_MEMORY_SCOPE_AGENT)
                + __hip_atomic_load(&base[tid + 64], __ATOMIC_ACQUIRE,
                                    __HIP_MEMORY_SCOPE_AGENT);
        if (tid < NBLK - 128)           // 176 - 128 = 48 extras
            v += __hip_atomic_load(&base[tid + 128], __ATOMIC_ACQUIRE,
                                   __HIP_MEMORY_SCOPE_AGENT);
        // fixed tid-ordered tree -> bitwise-deterministic total
        #pragma unroll
        for (int off = 32; off >= 1; off >>= 1)
            v += __shfl_down(v, off, 64);
        if (tid == 0) {
            const float scale = 1.0f / (81.0f * (float)HO * (float)HO);
            out[b] = v * scale;
        }
    }
}

extern "C" void kernel_launch(void* const* d_in, const int* in_sizes, int n_in,
                              void* d_out, int out_size, void* d_ws, size_t ws_size,
                              hipStream_t stream) {
    const float* x1 = (const float*)d_in[0];
    const float* x2 = (const float*)d_in[1];
    float* out = (float*)d_out;
    float* ws  = (float*)d_ws;   // f32[0..1407] partials; u32[4096 + b*64] counters (~18 KB)

    dim3 block(128);
    dim3 grid(GX, GY, 8);        // 11 x 16 x 8 = 1408 blocks
    ncc_kernel<<<grid, block, 0, stream>>>(x1, x2, ws, out);
}

// Round 11
// 11.263 us; speedup vs baseline: 1.0617x; 1.0617x over previous
//
#include <hip/hip_runtime.h>

#define EPSF 1e-4f
#define H    256
#define W    256
#define HO   248           // valid output dim: 256 - 9 + 1
#define OW   24            // output columns per block
#define OH   16            // output rows per block
#define CSTR 33            // padded LDS row stride
#define GX   11            // ceil(248/24)
#define GY   16            // ceil(248/16)
#define NBLK (GX*GY)       // 176 partials per batch

// Separable NCC, small tiles for latency hiding (5.5 blocks/CU co-resident,
// 2-wave barrier scope).
// Phase 1: vertical 9-window column sums of (a, b, a2, b2, ab) -> LDS.
// Phase 2: horizontal 9-window slide (3 outputs/thread), finalize, reduce.
// Final answer: rounds 3/6/7/10 all land at 11.4-12.0us across +-40% work
// deltas and 1-vs-2-kernel structures -> ~9.5us graph-replay/dispatch floor
// dominates; this variant is the fastest measured, absmax=0, deterministic,
// no cross-block protocols (grid.sync ~80us, fenced atomics +15us, relaxed
// protocols race across replays - all measured failures this session).
__global__ __launch_bounds__(128) void ncc_kernel(
    const float* __restrict__ x1, const float* __restrict__ x2,
    float* __restrict__ ws)
{
    __shared__ float C[5][OH][CSTR];   // 10560 B
    __shared__ float warp_part[2];

    const int b  = blockIdx.z;
    const int j0 = blockIdx.x * OW;
    const int i0 = blockIdx.y * OH;
    const int tid = threadIdx.x;

    const float* p1 = x1 + (size_t)b * (H * W);
    const float* p2 = x2 + (size_t)b * (H * W);

    // ---------------- Phase 1: vertical column sums ----------------
    // thread -> (pixel column c = tid&31, row-group g = tid>>5); each of the
    // 4 groups produces 4 output rows via a register slide (12 input rows).
    {
        const int c = tid & 31;        // 0..31
        const int g = tid >> 5;        // 0..3
        const int j = j0 + c;
        const bool jok = (j < W);
        const int ibase = i0 + g * 4;

        float av[12], bv[12];
        #pragma unroll
        for (int r = 0; r < 12; ++r) {
            const int i = ibase + r;
            const bool ok = jok && (i < H);
            av[r] = ok ? p1[i * W + j] : 0.0f;
            bv[r] = ok ? p2[i * W + j] : 0.0f;
        }

        float s1 = 0.0f, s2 = 0.0f, s11 = 0.0f, s22 = 0.0f, s12 = 0.0f;
        #pragma unroll
        for (int r = 0; r < 9; ++r) {
            s1 += av[r];
            s2 += bv[r];
            s11 = fmaf(av[r], av[r], s11);
            s22 = fmaf(bv[r], bv[r], s22);
            s12 = fmaf(av[r], bv[r], s12);
        }
        const int t0 = g * 4;
        C[0][t0][c] = s1;  C[1][t0][c] = s2;
        C[2][t0][c] = s11; C[3][t0][c] = s22; C[4][t0][c] = s12;

        #pragma unroll
        for (int tt = 1; tt < 4; ++tt) {
            const float an = av[tt + 8], bn = bv[tt + 8];
            const float ao = av[tt - 1], bo = bv[tt - 1];
            s1 += an - ao;
            s2 += bn - bo;
            s11 = fmaf(an, an, s11); s11 = fmaf(-ao, ao, s11);
            s22 = fmaf(bn, bn, s22); s22 = fmaf(-bo, bo, s22);
            s12 = fmaf(an, bn, s12); s12 = fmaf(-ao, bo, s12);
            const int t = t0 + tt;
            C[0][t][c] = s1;  C[1][t][c] = s2;
            C[2][t][c] = s11; C[3][t][c] = s22; C[4][t][c] = s12;
        }
    }
    __syncthreads();

    // ---------------- Phase 2: horizontal sliding window ----------------
    // thread -> (output row t = tid&15, column group jg = tid>>4 of 3 outputs)
    // bank = (t + 3*jg + k) mod 32 -> ~2-way aliasing (free).
    float contrib = 0.0f;
    {
        const int t   = tid & 15;      // 0..15
        const int jg  = tid >> 4;      // 0..7
        const int jc0 = jg * 3;
        const int t_out = i0 + t;

        float cv[11];
        float Wq[3][5];
        #pragma unroll
        for (int q = 0; q < 5; ++q) {
            #pragma unroll
            for (int k = 0; k < 11; ++k)
                cv[k] = C[q][t][jc0 + k];
            float w = cv[0];
            #pragma unroll
            for (int k = 1; k < 9; ++k) w += cv[k];
            Wq[0][q] = w;
            Wq[1][q] = Wq[0][q] - cv[0] + cv[9];
            Wq[2][q] = Wq[1][q] - cv[1] + cv[10];
        }

        const float inv_n = 1.0f / 81.0f;
        #pragma unroll
        for (int m = 0; m < 3; ++m) {
            const int j_out = j0 + jc0 + m;
            if (t_out < HO && j_out < HO) {
                const float s1  = Wq[m][0], s2  = Wq[m][1];
                const float s11 = Wq[m][2], s22 = Wq[m][3], s12 = Wq[m][4];
                const float mu1 = s1 * inv_n;
                const float mu2 = s2 * inv_n;
                const float v1  = fmaf(-mu1, mu1, s11 * inv_n) + EPSF;
                const float v2  = fmaf(-mu2, mu2, s22 * inv_n) + EPSF;
                const float cross = fmaf(-mu1, s2, s12);
                contrib += cross * rsqrtf(v1 * v2);
            }
        }
    }

    // ---------------- block reduce -> one partial per block ----------------
    #pragma unroll
    for (int off = 32; off >= 1; off >>= 1)
        contrib += __shfl_down(contrib, off, 64);

    const int lane = tid & 63;
    const int wid  = tid >> 6;
    if (lane == 0) warp_part[wid] = contrib;
    __syncthreads();

    if (tid == 0) {
        const int blk = blockIdx.y * GX + blockIdx.x;
        ws[b * NBLK + blk] = warp_part[0] + warp_part[1];
    }
}

// Stage 2: sum NBLK partials per batch, scale, write out[b]. Overwrites out
// fully every call (no memset needed).
__global__ __launch_bounds__(256) void ncc_reduce_kernel(
    const float* __restrict__ ws, float* __restrict__ out)
{
    const int b   = blockIdx.x;
    const int tid = threadIdx.x;

    float v = (tid < NBLK) ? ws[b * NBLK + tid] : 0.0f;

    #pragma unroll
    for (int off = 32; off >= 1; off >>= 1)
        v += __shfl_down(v, off, 64);

    __shared__ float wp[4];
    const int lane = tid & 63;
    const int wv   = tid >> 6;
    if (lane == 0) wp[wv] = v;
    __syncthreads();

    if (tid == 0) {
        const float scale = 1.0f / (81.0f * (float)HO * (float)HO);
        out[b] = (wp[0] + wp[1] + wp[2] + wp[3]) * scale;
    }
}

extern "C" void kernel_launch(void* const* d_in, const int* in_sizes, int n_in,
                              void* d_out, int out_size, void* d_ws, size_t ws_size,
                              hipStream_t stream) {
    const float* x1 = (const float*)d_in[0];
    const float* x2 = (const float*)d_in[1];
    float* out = (float*)d_out;
    float* ws  = (float*)d_ws;   // 8 * 176 floats used

    dim3 block(128);
    dim3 grid(GX, GY, 8);        // 11 x 16 x 8 = 1408 blocks
    ncc_kernel<<<grid, block, 0, stream>>>(x1, x2, ws);
    ncc_reduce_kernel<<<dim3(8), dim3(256), 0, stream>>>(ws, out);
}